// Round 4
// baseline (224.456 us; speedup 1.0000x reference)
//
#include <hip/hip_runtime.h>
#include <math.h>

// Problem constants
constexpr int BN  = 16;    // batch
constexpr int HH  = 224;
constexpr int WW  = 224;
constexpr int CI  = 8;     // input channels
constexpr int FF  = 256;   // filter feature dim
constexpr int NC  = 16;    // output channels
constexpr int NP  = 1152;  // CI*NC*3*3 dynamic params per sample
// patch index p = cin*9 + dy*3 + dx  (p < 72), w[b][p][c] = dyn[b][p*16+c]
// float4 index for (cin,dy,dx, c-quad cq) = cin*36 + dy*12 + dx*4 + cq

__device__ __forceinline__ float elu_f(float x) {
    return x > 0.0f ? x : (__expf(x) - 1.0f);
}

// --------- fused kernel 1: h = elu(fi@W1+b1); dyn = h@Wd+bd; bias = h@Wb+bb+dfn
// grid 16 blocks (1 per sample), 256 threads
__global__ __launch_bounds__(256) void k_hdyn(const float* __restrict__ fi,
                                              const float* __restrict__ W1,
                                              const float* __restrict__ b1,
                                              const float* __restrict__ Wd,
                                              const float* __restrict__ bd,
                                              const float* __restrict__ Wb,
                                              const float* __restrict__ bb,
                                              const float* __restrict__ dfn,
                                              float* __restrict__ w_out,
                                              float* __restrict__ bias_out) {
    __shared__ float xl[FF];
    __shared__ float hl[FF];
    const int b = blockIdx.x;
    const int t = threadIdx.x;               // 0..255

    xl[t] = fi[b * FF + t];
    __syncthreads();

    float acc = b1[t];
#pragma unroll 8
    for (int k = 0; k < FF; ++k) acc = fmaf(xl[k], W1[k * FF + t], acc);
    hl[t] = elu_f(acc);
    __syncthreads();

    // dyn columns: 1152 = 4*256 + 128
#pragma unroll 1
    for (int j = 0; j < 4; ++j) {
        const int i = j * 256 + t;
        float a = bd[i];
#pragma unroll 8
        for (int k = 0; k < FF; ++k) a = fmaf(hl[k], Wd[k * NP + i], a);
        w_out[b * NP + i] = a;
    }
    if (t < 128) {
        const int i = 1024 + t;
        float a = bd[i];
#pragma unroll 8
        for (int k = 0; k < FF; ++k) a = fmaf(hl[k], Wd[k * NP + i], a);
        w_out[b * NP + i] = a;
    }
    if (t < NC) {
        float a = bb[t] + dfn[t];
#pragma unroll 8
        for (int k = 0; k < FF; ++k) a = fmaf(hl[k], Wb[k * NC + t], a);
        bias_out[b * NC + t] = a;
    }
}

// ---------------- kernel 3: dynamic 3x3 conv + bias + elu --------------------
// Channel-split: each of the 4 waves in a block computes a 4-channel quad for
// the SAME 16x16 pixel tile. Per tap a wave reads ONE float4 of weights
// (wave-uniform LDS broadcast), rotated 2 taps ahead in registers.
// 4 px/thread along x; next input row prefetched into u[] during the FMA block.
// Forced-live set: acc 16 + rv 48 + u 48 + w 12 + addr ~= 145 regs.
// launch_bounds(256,3): cap ~170 VGPR, 3 waves/SIMD.
__global__ __launch_bounds__(256, 3) void k_conv(const float* __restrict__ in,
                                                 const float* __restrict__ w_all,
                                                 const float* __restrict__ bias_all,
                                                 float* __restrict__ out) {
    __shared__ float4 lw[NP / 4];            // 288 float4 = 4.6 KB

    const int b = blockIdx.z;
    const int t = threadIdx.x;               // 0..255

    const float4* __restrict__ wsrc = (const float4*)(w_all + (size_t)b * NP);
    lw[t] = wsrc[t];
    if (t < 32) lw[t + 256] = wsrc[t + 256];
    __syncthreads();

    const int cq   = t >> 6;                 // wave id = output channel quad
    const int lane = t & 63;
    const int tx   = lane & 3;               // 0..3  -> x block of 4
    const int ty   = lane >> 2;              // 0..15 -> row
    const int x0   = blockIdx.x * 16 + tx * 4;
    const int y    = blockIdx.y * 16 + ty;

    // ---- init accumulators with this quad's bias ----
    const float4 bv = ((const float4*)(bias_all + b * NC))[cq];
    float acc[4][4];
#pragma unroll
    for (int p = 0; p < 4; ++p) {
        acc[p][0] = bv.x; acc[p][1] = bv.y; acc[p][2] = bv.z; acc[p][3] = bv.w;
    }

    // ---- column indices / validity (cols x0-1 .. x0+4) ----
    int  cx[6];
    bool okc[6];
#pragma unroll
    for (int i = 0; i < 6; ++i) {
        const int c = x0 - 1 + i;
        okc[i] = (unsigned)c < (unsigned)WW;
        cx[i]  = min(max(c, 0), WW - 1);
    }

    const float* __restrict__ base = in + ((size_t)b * HH) * WW * CI;

    // ---- preload input row for dy=0 (row y-1, clamped) ----
    float4 u[12];
    {
        const int cy = max(y - 1, 0);
        const float* __restrict__ rowp = base + (size_t)cy * WW * CI;
#pragma unroll
        for (int i = 0; i < 6; ++i) {
            const float4* cp = (const float4*)(rowp + (size_t)cx[i] * CI);
            u[2 * i]     = cp[0];
            u[2 * i + 1] = cp[1];
        }
    }

#pragma unroll 1
    for (int dy = 0; dy < 3; ++dy) {
        const bool oky = (unsigned)(y + dy - 1) < (unsigned)HH;

        // fold u into masked rv
        float rv[48];
#pragma unroll
        for (int i = 0; i < 6; ++i) {
            const bool ok = oky && okc[i];
            const float4 a = u[2 * i], c = u[2 * i + 1];
            rv[i * 8 + 0] = ok ? a.x : 0.0f;
            rv[i * 8 + 1] = ok ? a.y : 0.0f;
            rv[i * 8 + 2] = ok ? a.z : 0.0f;
            rv[i * 8 + 3] = ok ? a.w : 0.0f;
            rv[i * 8 + 4] = ok ? c.x : 0.0f;
            rv[i * 8 + 5] = ok ? c.y : 0.0f;
            rv[i * 8 + 6] = ok ? c.z : 0.0f;
            rv[i * 8 + 7] = ok ? c.w : 0.0f;
        }

        // issue next row's loads now — covered by the 24-tap FMA block
        if (dy < 2) {
            const int cy = min(y + dy, HH - 1);
            const float* __restrict__ rowp = base + (size_t)cy * WW * CI;
#pragma unroll
            for (int i = 0; i < 6; ++i) {
                const float4* cp = (const float4*)(rowp + (size_t)cx[i] * CI);
                u[2 * i]     = cp[0];
                u[2 * i + 1] = cp[1];
            }
        }

        // ---- 24 taps, weights 2 ahead in rotating registers ----
        const int wbase = dy * 12 + cq;
        float4 wA = lw[wbase + 0];           // tap 0: cin0,dx0
        float4 wB = lw[wbase + 4];           // tap 1: cin0,dx1
#pragma unroll
        for (int cin = 0; cin < 8; ++cin) {
#pragma unroll
            for (int dx = 0; dx < 3; ++dx) {
                const int tt = cin * 3 + dx;
                float4 wC = wA;
                if (tt + 2 < 24) {
                    const int nt = tt + 2;
                    wC = lw[wbase + (nt / 3) * 36 + (nt % 3) * 4];
                }
#pragma unroll
                for (int p = 0; p < 4; ++p) {
                    const float v = rv[(p + dx) * 8 + cin];
                    acc[p][0] = fmaf(v, wA.x, acc[p][0]);
                    acc[p][1] = fmaf(v, wA.y, acc[p][1]);
                    acc[p][2] = fmaf(v, wA.z, acc[p][2]);
                    acc[p][3] = fmaf(v, wA.w, acc[p][3]);
                }
                wA = wB; wB = wC;
            }
        }
    }

    // ---- epilogue: elu + store 4 pixels x this channel quad ----
    const size_t obase = ((size_t)b * HH + y) * WW + x0;
#pragma unroll
    for (int p = 0; p < 4; ++p) {
        float4 r;
        r.x = elu_f(acc[p][0]);
        r.y = elu_f(acc[p][1]);
        r.z = elu_f(acc[p][2]);
        r.w = elu_f(acc[p][3]);
        ((float4*)(out + (obase + p) * NC))[cq] = r;
    }
}

extern "C" void kernel_launch(void* const* d_in, const int* in_sizes, int n_in,
                              void* d_out, int out_size, void* d_ws, size_t ws_size,
                              hipStream_t stream) {
    const float* inpt = (const float*)d_in[0];
    const float* fi   = (const float*)d_in[1];
    const float* W1   = (const float*)d_in[2];
    const float* b1   = (const float*)d_in[3];
    const float* Wd   = (const float*)d_in[4];
    const float* bd   = (const float*)d_in[5];
    const float* Wb   = (const float*)d_in[6];
    const float* bb   = (const float*)d_in[7];
    const float* dfn  = (const float*)d_in[8];
    float* out = (float*)d_out;

    float* ws    = (float*)d_ws;
    float* h     = ws;                    // (unused scratch region kept)
    float* wDyn  = ws + 4096;             // 16*1152  = 18432 floats
    float* biasA = ws + 4096 + 18432;     // 16*16    = 256 floats
    (void)h;

    k_hdyn<<<16, 256, 0, stream>>>(fi, W1, b1, Wd, bd, Wb, bb, dfn, wDyn, biasA);
    k_conv<<<dim3(14, 14, BN), 256, 0, stream>>>(inpt, wDyn, biasA, out);
}